// Round 3
// baseline (5676.686 us; speedup 1.0000x reference)
//
#include <hip/hip_runtime.h>
#include <math.h>

#define B_   128
#define T_   512
#define RR   512
#define DTAU 0.2f

#define R_BLOCKS 32
#define B_BLOCKS 8
#define R_S  16
#define B_T  16
#define NWG  (R_BLOCKS * B_BLOCKS)
#define NTHR 256
#define LOSCALE 4096.0f
#define LOINV   (1.0f/4096.0f)

typedef _Float16 f16x8 __attribute__((ext_vector_type(8)));
typedef float f32x4 __attribute__((ext_vector_type(4)));

#define MFMA(A,B,C) __builtin_amdgcn_mfma_f32_16x16x32_f16(A, B, C, 0, 0, 0)

// ws layout in u32 units:
//   [0      .. 65536)  EX_H  : u32[128][512]
//   [65536  .. 131072) EX_RH : u32[128][512]
// Each u32 = hi f16 | lo' f16 << 16.  Bit 0 (hi-f16 LSB) carries the phase
// parity tag; lo is computed AFTER forcing the bit, so it compensates exactly.
// No flags, no atomics, no store drains: readers poll the data itself.
// Same-address store ordering across timesteps is established by observation:
// each WG polls its OWN slots (its rows cover all k, including the slots it
// publishes) before the next write to those slots, so the previous store
// provably reached the coherence point; the phase barrier orders the rest of
// the WG behind that observation.
#define EXH_OFF  0
#define EXRH_OFF 65536
#define EX_WORDS 131072

__global__ void init_parity(unsigned int* ws) {
    int i = blockIdx.x * 256 + threadIdx.x;
    if (i < EX_WORDS) ws[i] = 1u;   // parity=1 everywhere; first expected parity is 0
}

__device__ __forceinline__ unsigned long long ald64(const unsigned long long* p) {
    return __hip_atomic_load(p, __ATOMIC_RELAXED, __HIP_MEMORY_SCOPE_AGENT);
}

// Publish one value: force hi-f16 LSB := parity, recompute lo against the
// forced hi (exact compensation), store one u32 agent-scope.  NO drain after:
// visibility is pulled by consumers, ordering by the observation argument.
__device__ __forceinline__ void publish_val(unsigned int* ex, int idx, float v,
                                            unsigned int par) {
    _Float16 vh = (_Float16)v;
    unsigned short hb =
        (unsigned short)((__builtin_bit_cast(unsigned short, vh) & 0xfffeu) | par);
    vh = __builtin_bit_cast(_Float16, hb);
    _Float16 vl = (_Float16)((v - (float)vh) * LOSCALE);
    unsigned int pk = (unsigned int)hb
                    | ((unsigned int)__builtin_bit_cast(unsigned short, vl) << 16);
    __hip_atomic_store(ex + idx, pk, __ATOMIC_RELAXED, __HIP_MEMORY_SCOPE_AGENT);
}

// Two-stage poll+load (round-1 shape: the measured-best protocol).
// Stage 1: light pre-poll — 4 b64/lane covering 2 of 16 entries of EVERY
// producer slice in this wave's k-range (a slice's 16 stores come from one
// producer instruction, so 2 entries are a reliable readiness proxy); cheap
// loop body keeps detection granularity fine and MALL traffic low.
// Stage 2: single full fetch verifying EVERY u32's parity before use
// (re-loops only on a rare straggler race).
__device__ __forceinline__ void poll_frags(const unsigned int* ex, int kb, int lane,
                                           unsigned int want, f16x8* hi, f16x8* lo)
{
    const int b  = lane & 15;
    const int qd = lane >> 4;
    const unsigned long long wm = 0x0000000100000001ULL * (unsigned long long)want;
    const unsigned long long* p0 =
        (const unsigned long long*)(ex + (size_t)b * RR + kb + qd * 8);

    for (;;) {
        unsigned long long c0 = ald64(p0);
        unsigned long long c1 = ald64(p0 + 16);
        unsigned long long c2 = ald64(p0 + 32);
        unsigned long long c3 = ald64(p0 + 48);
        unsigned long long acc = (c0 ^ wm) | (c1 ^ wm) | (c2 ^ wm) | (c3 ^ wm);
        unsigned int a = (unsigned int)acc | (unsigned int)(acc >> 32);
        if (__all((a & 1u) == 0u)) break;
        __builtin_amdgcn_s_sleep(1);
    }
    __asm__ volatile("" ::: "memory");   // keep data loads after the spin exits

    for (;;) {
        unsigned long long d[16];
        #pragma unroll
        for (int kc = 0; kc < 4; ++kc)
            #pragma unroll
            for (int m = 0; m < 4; ++m)
                d[kc * 4 + m] = ald64(p0 + kc * 16 + m);
        unsigned long long acc = 0ull;
        #pragma unroll
        for (int i = 0; i < 16; ++i) acc |= d[i] ^ wm;
        unsigned int a = (unsigned int)acc | (unsigned int)(acc >> 32);
        if (__all((a & 1u) == 0u)) {
            #pragma unroll
            for (int kc = 0; kc < 4; ++kc) {
                union { f16x8 v; unsigned int u[4]; } H, L;
                #pragma unroll
                for (int m = 0; m < 4; ++m) {
                    unsigned int e0 = (unsigned int)d[kc * 4 + m];
                    unsigned int e1 = (unsigned int)(d[kc * 4 + m] >> 32);
                    H.u[m] = (e0 & 0xffffu) | (e1 << 16);
                    L.u[m] = (e0 >> 16) | (e1 & 0xffff0000u);
                }
                hi[kc] = H.v; lo[kc] = L.v;
            }
            __asm__ volatile("" ::: "memory");
            return;
        }
    }
}

// Pack 8 contiguous fp32 weights into hi + scaled-lo f16 fragments.
__device__ __forceinline__ void packW(const float* p, f16x8& hi, f16x8& lo) {
    float4 a = *(const float4*)p;
    float4 c = *(const float4*)(p + 4);
    float w[8] = {a.x, a.y, a.z, a.w, c.x, c.y, c.z, c.w};
    f16x8 H, L;
    #pragma unroll
    for (int j = 0; j < 8; ++j) {
        _Float16 h = (_Float16)w[j];
        H[j] = h;
        L[j] = (_Float16)((w[j] - (float)h) * LOSCALE);
    }
    hi = H; lo = L;
}

// LDS reduction planes: 1=r (phase A), 0=z and 2=u (phase B).  Disjoint
// planes + the per-phase barrier keep one __syncthreads per phase.
#define RED(g,w,m,n) sred[((((g)*4+(w))*16+(m))*17)+(n)]

__global__ __launch_bounds__(NTHR, 1)
void rnn_persistent(const float* __restrict__ x,
                    const float* __restrict__ init_state,
                    const float* __restrict__ W_enc,
                    const float* __restrict__ W_wz,
                    const float* __restrict__ W_uz,
                    const float* __restrict__ W_wr,
                    const float* __restrict__ W_ur,
                    const float* __restrict__ W_wh,
                    const float* __restrict__ W_uh,
                    float* __restrict__ h_out,   // [B][T][RR]
                    unsigned int* __restrict__ ws)
{
    const int wg = blockIdx.x;
    const int bg = wg & 7;           // batch group 0..7 (same XCD mod-8: perf only)
    const int rb = wg >> 3;          // r-slice 0..31
    const int b0 = bg * B_T;
    const int i0 = rb * R_S;

    unsigned int* exh  = ws + EXH_OFF  + (size_t)b0 * RR;
    unsigned int* exrh = ws + EXRH_OFF + (size_t)b0 * RR;

    __shared__ float sred[3 * 4 * 16 * 17];

    const int tid  = threadIdx.x;
    const int lane = tid & 63;
    const int wv   = tid >> 6;       // wave 0..3, owns K-slice [wv*128, wv*128+128)
    const int kb   = wv * 128;
    const int qd   = lane >> 4;
    const int nn   = lane & 15;
    const int bq   = tid >> 4;       // batch 0..15 (pointwise mapping)
    const int iq   = tid & 15;       // row-in-slice 0..15
    const int ig   = i0 + iq;

    const float wz0 = W_wz[ig * 2], wz1 = W_wz[ig * 2 + 1];
    const float wr0 = W_wr[ig * 2], wr1 = W_wr[ig * 2 + 1];
    const float wh0 = W_wh[ig * 2], wh1 = W_wh[ig * 2 + 1];

    // ---------------- encoder: h0 = init_state @ W_enc^T (fp32 exact) ----------------
    {
        float we[4][8];
        const int myrow = i0 + wv * 4;
        #pragma unroll
        for (int ii = 0; ii < 4; ++ii)
            #pragma unroll
            for (int j = 0; j < 8; ++j)
                we[ii][j] = W_enc[(size_t)(myrow + ii) * RR + lane + 64 * j];
        for (int b = 0; b < B_T; ++b) {
            float is[8];
            #pragma unroll
            for (int j = 0; j < 8; ++j)
                is[j] = init_state[(size_t)(b0 + b) * RR + lane + 64 * j];
            #pragma unroll
            for (int ii = 0; ii < 4; ++ii) {
                float acc = 0.f;
                #pragma unroll
                for (int j = 0; j < 8; ++j) acc += we[ii][j] * is[j];
                #pragma unroll
                for (int off = 32; off > 0; off >>= 1) acc += __shfl_xor(acc, off, 64);
                if (lane == 0) RED(0, 0, b, wv * 4 + ii) = acc;
            }
        }
    }
    __syncthreads();
    float hprev = RED(0, 0, bq, iq);
    publish_val(exh, bq * RR + i0 + iq, hprev, 0u);     // exh write #0, parity 0
    __syncthreads();   // hprev reads done before any wave writes RED plane 0

    // ---------------- pack recurrent weights to B-fragments in registers ----------------
    f16x8 wzh[4], wzl[4], wrh[4], wrl[4], whh[4], whl[4];
    #pragma unroll
    for (int kc = 0; kc < 4; ++kc) {
        const int kg = kb + kc * 32 + qd * 8;
        packW(&W_uz[(size_t)(i0 + nn) * RR + kg], wzh[kc], wzl[kc]);
        packW(&W_ur[(size_t)(i0 + nn) * RR + kg], wrh[kc], wrl[kc]);
        packW(&W_uh[(size_t)(i0 + nn) * RR + kg], whh[kc], whl[kc]);
    }

    // ---------------- time loop ----------------
    for (int t = 0; t < T_; ++t) {
        const unsigned int parA = (unsigned int)(t & 1);   // exh write #t / exrh write #t
        const float2 xv = ((const float2*)x)[(size_t)(b0 + bq) * T_ + t];

        // ===== phase A: r only (z's MFMAs are deferred to phase B) =====
        f16x8 ah[4], al[4];
        poll_frags(exh, kb, lane, parA, ah, al);

        f32x4 rM = {0,0,0,0}, rC = {0,0,0,0};
        #pragma unroll
        for (int kc = 0; kc < 4; ++kc) {
            rM = MFMA(ah[kc], wrh[kc], rM);
            rC = MFMA(ah[kc], wrl[kc], rC);
            rC = MFMA(al[kc], wrh[kc], rC);
        }
        #pragma unroll
        for (int rg = 0; rg < 4; ++rg)
            RED(1, wv, qd * 4 + rg, nn) = rM[rg] + rC[rg] * LOINV;
        __syncthreads();

        float rsum = 0.f;
        #pragma unroll
        for (int w = 0; w < 4; ++w) rsum += RED(1, w, bq, iq);
        const float xr = xv.x * wr0 + xv.y * wr1;
        const float r  = 1.f / (1.f + expf(-(xr + rsum)));
        publish_val(exrh, bq * RR + i0 + iq, r * hprev, parA);

        // ===== phase B: u (fresh frags) + z (retained exh frags), h update =====
        f16x8 bh[4], bl[4];
        poll_frags(exrh, kb, lane, parA, bh, bl);

        f32x4 uM = {0,0,0,0}, uC = {0,0,0,0}, zM = {0,0,0,0}, zC = {0,0,0,0};
        #pragma unroll
        for (int kc = 0; kc < 4; ++kc) {
            uM = MFMA(bh[kc], whh[kc], uM);
            uC = MFMA(bh[kc], whl[kc], uC);
            uC = MFMA(bl[kc], whh[kc], uC);
            zM = MFMA(ah[kc], wzh[kc], zM);
            zC = MFMA(ah[kc], wzl[kc], zC);
            zC = MFMA(al[kc], wzh[kc], zC);
        }
        #pragma unroll
        for (int rg = 0; rg < 4; ++rg) {
            RED(2, wv, qd * 4 + rg, nn) = uM[rg] + uC[rg] * LOINV;
            RED(0, wv, qd * 4 + rg, nn) = zM[rg] + zC[rg] * LOINV;
        }
        __syncthreads();

        float usum = 0.f, zsum = 0.f;
        #pragma unroll
        for (int w = 0; w < 4; ++w) { usum += RED(2, w, bq, iq); zsum += RED(0, w, bq, iq); }
        const float u = xv.x * wh0 + xv.y * wh1 + usum;
        const float e2 = expf(-2.f * fabsf(u));
        const float th = copysignf((1.f - e2) / (1.f + e2), u);
        const float xz = xv.x * wz0 + xv.y * wz1;
        const float z  = 1.f / (1.f + expf(-(xz + zsum)));
        const float hn = hprev + DTAU * (z - 1.f) * (hprev - th);
        hprev = hn;
        publish_val(exh, bq * RR + i0 + iq, hn, parA ^ 1u);   // exh write #t+1
        h_out[((size_t)(b0 + bq) * T_ + t) * RR + i0 + iq] = hn;  // off the critical chain
    }
}

// ---------------- decoder: Y[m][n] = sum_k H[m][k] * Wd[n][k] (fp32) ----------------
#define DT_M 64
#define DT_N 64
#define DT_K 32

__global__ __launch_bounds__(256)
void decoder_gemm(const float* __restrict__ H, const float* __restrict__ Wd,
                  float* __restrict__ Y)
{
    __shared__ float As[DT_K][DT_M + 1];
    __shared__ float Bs[DT_K][DT_N + 1];
    const int m0 = blockIdx.x * DT_M;
    const int n0 = blockIdx.y * DT_N;
    const int tid = threadIdx.x;
    const int tx = tid % 16, ty = tid / 16;
    float acc[4][4] = {};

    for (int k0 = 0; k0 < RR; k0 += DT_K) {
        #pragma unroll
        for (int l = 0; l < 2; ++l) {
            int idx = tid + l * 256;
            int row = idx / (DT_K / 4);
            int kc  = idx % (DT_K / 4);
            float4 v = ((const float4*)&H[(size_t)(m0 + row) * RR + k0])[kc];
            As[kc * 4 + 0][row] = v.x; As[kc * 4 + 1][row] = v.y;
            As[kc * 4 + 2][row] = v.z; As[kc * 4 + 3][row] = v.w;
        }
        #pragma unroll
        for (int l = 0; l < 2; ++l) {
            int idx = tid + l * 256;
            int row = idx / (DT_K / 4);
            int kc  = idx % (DT_K / 4);
            float4 v = ((const float4*)&Wd[(size_t)(n0 + row) * RR + k0])[kc];
            Bs[kc * 4 + 0][row] = v.x; Bs[kc * 4 + 1][row] = v.y;
            Bs[kc * 4 + 2][row] = v.z; Bs[kc * 4 + 3][row] = v.w;
        }
        __syncthreads();
        #pragma unroll
        for (int k = 0; k < DT_K; ++k) {
            float a[4], bb[4];
            #pragma unroll
            for (int i2 = 0; i2 < 4; ++i2) a[i2] = As[k][ty * 4 + i2];
            #pragma unroll
            for (int j2 = 0; j2 < 4; ++j2) bb[j2] = Bs[k][tx * 4 + j2];
            #pragma unroll
            for (int i2 = 0; i2 < 4; ++i2)
                #pragma unroll
                for (int j2 = 0; j2 < 4; ++j2)
                    acc[i2][j2] += a[i2] * bb[j2];
        }
        __syncthreads();
    }
    #pragma unroll
    for (int i2 = 0; i2 < 4; ++i2) {
        float4 v = make_float4(acc[i2][0], acc[i2][1], acc[i2][2], acc[i2][3]);
        ((float4*)&Y[(size_t)(m0 + ty * 4 + i2) * RR + n0])[tx] = v;
    }
}

extern "C" void kernel_launch(void* const* d_in, const int* in_sizes, int n_in,
                              void* d_out, int out_size, void* d_ws, size_t ws_size,
                              hipStream_t stream) {
    const float* x          = (const float*)d_in[0];
    const float* init_state = (const float*)d_in[1];
    const float* W_enc      = (const float*)d_in[2];
    const float* W_wz       = (const float*)d_in[3];
    const float* W_uz       = (const float*)d_in[4];
    const float* W_wr       = (const float*)d_in[5];
    const float* W_ur       = (const float*)d_in[6];
    const float* W_wh       = (const float*)d_in[7];
    const float* W_uh       = (const float*)d_in[8];
    const float* W_dec      = (const float*)d_in[9];

    float* h_out = (float*)d_out;                          // [128][512][512]
    float* y_out = (float*)d_out + (size_t)B_ * T_ * RR;   // [128][512][512]
    unsigned int* ws = (unsigned int*)d_ws;

    init_parity<<<(EX_WORDS + 255) / 256, 256, 0, stream>>>(ws);
    rnn_persistent<<<NWG, NTHR, 0, stream>>>(
        x, init_state, W_enc, W_wz, W_uz, W_wr, W_ur, W_wh, W_uh, h_out, ws);
    decoder_gemm<<<dim3((B_ * T_) / DT_M, RR / DT_N), 256, 0, stream>>>(
        h_out, W_dec, y_out);
}

// Round 4
// 4219.458 us; speedup vs baseline: 1.3454x; 1.3454x over previous
//
#include <hip/hip_runtime.h>
#include <math.h>

#define B_   128
#define T_   512
#define RR   512
#define DTAU 0.2f

#define R_BLOCKS 32
#define B_BLOCKS 8
#define R_S  16
#define B_T  16
#define NWG  (R_BLOCKS * B_BLOCKS)
#define NTHR 256
#define LOSCALE 4096.0f
#define LOINV   (1.0f/4096.0f)

typedef _Float16 f16x8 __attribute__((ext_vector_type(8)));
typedef float f32x4 __attribute__((ext_vector_type(4)));

#define MFMA(A,B,C) __builtin_amdgcn_mfma_f32_16x16x32_f16(A, B, C, 0, 0, 0)

// ws layout in u32 units:
//   [0      .. 65536)  EX_H  : u32[128][512]
//   [65536  .. 131072) EX_RH : u32[128][512]
// Each u32 = hi f16 | lo' f16 << 16.  Bit 0 (hi-f16 LSB) carries the phase
// parity tag; lo is computed AFTER forcing the bit, so it compensates exactly.
// No flags, no atomics.  Producers DO drain (s_waitcnt vmcnt(0)) after each
// publish: measured (r1 vs r2/r3), the drain paces the producer until its
// store is ack'd at the coherence point — without it, consumer spin traffic
// doubles (FETCH 149->316 MB) and the phase period grows ~40%.
#define EXH_OFF  0
#define EXRH_OFF 65536
#define EX_WORDS 131072

__global__ void init_parity(unsigned int* ws) {
    int i = blockIdx.x * 256 + threadIdx.x;
    if (i < EX_WORDS) ws[i] = 1u;   // parity=1 everywhere; first expected parity is 0
}

__device__ __forceinline__ unsigned long long ald64(const unsigned long long* p) {
    return __hip_atomic_load(p, __ATOMIC_RELAXED, __HIP_MEMORY_SCOPE_AGENT);
}

// Publish one value: force hi-f16 LSB := parity, recompute lo against the
// forced hi (exact compensation), store one u32 agent-scope.
__device__ __forceinline__ void publish_val(unsigned int* ex, int idx, float v,
                                            unsigned int par) {
    _Float16 vh = (_Float16)v;
    unsigned short hb =
        (unsigned short)((__builtin_bit_cast(unsigned short, vh) & 0xfffeu) | par);
    vh = __builtin_bit_cast(_Float16, hb);
    _Float16 vl = (_Float16)((v - (float)vh) * LOSCALE);
    unsigned int pk = (unsigned int)hb
                    | ((unsigned int)__builtin_bit_cast(unsigned short, vl) << 16);
    __hip_atomic_store(ex + idx, pk, __ATOMIC_RELAXED, __HIP_MEMORY_SCOPE_AGENT);
}

// Two-stage poll+load (measured-best r1 protocol).
// Stage 1: light pre-poll — 4 b64/lane covering 2 of 16 entries of EVERY
// producer slice in this wave's k-range; cheap body keeps detection fine-
// grained and MALL traffic low.
// Stage 2: single full fetch verifying EVERY u32's parity before use
// (re-loops only on a rare straggler race).
__device__ __forceinline__ void poll_frags(const unsigned int* ex, int kb, int lane,
                                           unsigned int want, f16x8* hi, f16x8* lo)
{
    const int b  = lane & 15;
    const int qd = lane >> 4;
    const unsigned long long wm = 0x0000000100000001ULL * (unsigned long long)want;
    const unsigned long long* p0 =
        (const unsigned long long*)(ex + (size_t)b * RR + kb + qd * 8);

    for (;;) {
        unsigned long long c0 = ald64(p0);
        unsigned long long c1 = ald64(p0 + 16);
        unsigned long long c2 = ald64(p0 + 32);
        unsigned long long c3 = ald64(p0 + 48);
        unsigned long long acc = (c0 ^ wm) | (c1 ^ wm) | (c2 ^ wm) | (c3 ^ wm);
        unsigned int a = (unsigned int)acc | (unsigned int)(acc >> 32);
        if (__all((a & 1u) == 0u)) break;
        __builtin_amdgcn_s_sleep(1);
    }
    __asm__ volatile("" ::: "memory");   // keep data loads after the spin exits

    for (;;) {
        unsigned long long d[16];
        #pragma unroll
        for (int kc = 0; kc < 4; ++kc)
            #pragma unroll
            for (int m = 0; m < 4; ++m)
                d[kc * 4 + m] = ald64(p0 + kc * 16 + m);
        unsigned long long acc = 0ull;
        #pragma unroll
        for (int i = 0; i < 16; ++i) acc |= d[i] ^ wm;
        unsigned int a = (unsigned int)acc | (unsigned int)(acc >> 32);
        if (__all((a & 1u) == 0u)) {
            #pragma unroll
            for (int kc = 0; kc < 4; ++kc) {
                union { f16x8 v; unsigned int u[4]; } H, L;
                #pragma unroll
                for (int m = 0; m < 4; ++m) {
                    unsigned int e0 = (unsigned int)d[kc * 4 + m];
                    unsigned int e1 = (unsigned int)(d[kc * 4 + m] >> 32);
                    H.u[m] = (e0 & 0xffffu) | (e1 << 16);
                    L.u[m] = (e0 >> 16) | (e1 & 0xffff0000u);
                }
                hi[kc] = H.v; lo[kc] = L.v;
            }
            __asm__ volatile("" ::: "memory");
            return;
        }
    }
}

// Pack 8 contiguous fp32 weights into hi + scaled-lo f16 fragments.
__device__ __forceinline__ void packW(const float* p, f16x8& hi, f16x8& lo) {
    float4 a = *(const float4*)p;
    float4 c = *(const float4*)(p + 4);
    float w[8] = {a.x, a.y, a.z, a.w, c.x, c.y, c.z, c.w};
    f16x8 H, L;
    #pragma unroll
    for (int j = 0; j < 8; ++j) {
        _Float16 h = (_Float16)w[j];
        H[j] = h;
        L[j] = (_Float16)((w[j] - (float)h) * LOSCALE);
    }
    hi = H; lo = L;
}

// LDS reduction planes: 1=r (phase A), 0=z and 2=u (phase B).  Disjoint
// planes + the per-phase barrier keep one __syncthreads per phase.
#define RED(g,w,m,n) sred[((((g)*4+(w))*16+(m))*17)+(n)]

__global__ __launch_bounds__(NTHR, 1)
void rnn_persistent(const float* __restrict__ x,
                    const float* __restrict__ init_state,
                    const float* __restrict__ W_enc,
                    const float* __restrict__ W_wz,
                    const float* __restrict__ W_uz,
                    const float* __restrict__ W_wr,
                    const float* __restrict__ W_ur,
                    const float* __restrict__ W_wh,
                    const float* __restrict__ W_uh,
                    float* __restrict__ h_out,   // [B][T][RR]
                    unsigned int* __restrict__ ws)
{
    const int wg = blockIdx.x;
    const int bg = wg & 7;           // batch group 0..7 (same XCD mod-8: perf only)
    const int rb = wg >> 3;          // r-slice 0..31
    const int b0 = bg * B_T;
    const int i0 = rb * R_S;

    unsigned int* exh  = ws + EXH_OFF  + (size_t)b0 * RR;
    unsigned int* exrh = ws + EXRH_OFF + (size_t)b0 * RR;

    __shared__ float sred[3 * 4 * 16 * 17];

    const int tid  = threadIdx.x;
    const int lane = tid & 63;
    const int wv   = tid >> 6;       // wave 0..3, owns K-slice [wv*128, wv*128+128)
    const int kb   = wv * 128;
    const int qd   = lane >> 4;
    const int nn   = lane & 15;
    const int bq   = tid >> 4;       // batch 0..15 (pointwise mapping)
    const int iq   = tid & 15;       // row-in-slice 0..15
    const int ig   = i0 + iq;

    const float wz0 = W_wz[ig * 2], wz1 = W_wz[ig * 2 + 1];
    const float wr0 = W_wr[ig * 2], wr1 = W_wr[ig * 2 + 1];
    const float wh0 = W_wh[ig * 2], wh1 = W_wh[ig * 2 + 1];

    // ---------------- encoder: h0 = init_state @ W_enc^T (fp32 exact) ----------------
    {
        float we[4][8];
        const int myrow = i0 + wv * 4;
        #pragma unroll
        for (int ii = 0; ii < 4; ++ii)
            #pragma unroll
            for (int j = 0; j < 8; ++j)
                we[ii][j] = W_enc[(size_t)(myrow + ii) * RR + lane + 64 * j];
        for (int b = 0; b < B_T; ++b) {
            float is[8];
            #pragma unroll
            for (int j = 0; j < 8; ++j)
                is[j] = init_state[(size_t)(b0 + b) * RR + lane + 64 * j];
            #pragma unroll
            for (int ii = 0; ii < 4; ++ii) {
                float acc = 0.f;
                #pragma unroll
                for (int j = 0; j < 8; ++j) acc += we[ii][j] * is[j];
                #pragma unroll
                for (int off = 32; off > 0; off >>= 1) acc += __shfl_xor(acc, off, 64);
                if (lane == 0) RED(0, 0, b, wv * 4 + ii) = acc;
            }
        }
    }
    __syncthreads();
    float hprev = RED(0, 0, bq, iq);
    publish_val(exh, bq * RR + i0 + iq, hprev, 0u);     // exh write #0, parity 0
    __asm__ volatile("s_waitcnt vmcnt(0)" ::: "memory");
    __syncthreads();   // hprev reads done before any wave writes RED plane 0

    // ---------------- pack recurrent weights to B-fragments in registers ----------------
    f16x8 wzh[4], wzl[4], wrh[4], wrl[4], whh[4], whl[4];
    #pragma unroll
    for (int kc = 0; kc < 4; ++kc) {
        const int kg = kb + kc * 32 + qd * 8;
        packW(&W_uz[(size_t)(i0 + nn) * RR + kg], wzh[kc], wzl[kc]);
        packW(&W_ur[(size_t)(i0 + nn) * RR + kg], wrh[kc], wrl[kc]);
        packW(&W_uh[(size_t)(i0 + nn) * RR + kg], whh[kc], whl[kc]);
    }

    // ---------------- time loop ----------------
    for (int t = 0; t < T_; ++t) {
        const unsigned int parA = (unsigned int)(t & 1);   // exh write #t / exrh write #t
        const float2 xv = ((const float2*)x)[(size_t)(b0 + bq) * T_ + t];

        // ===== phase A: r only (z's MFMAs are deferred to phase B) =====
        f16x8 ah[4], al[4];
        poll_frags(exh, kb, lane, parA, ah, al);

        f32x4 rM = {0,0,0,0}, rC = {0,0,0,0};
        #pragma unroll
        for (int kc = 0; kc < 4; ++kc) {
            rM = MFMA(ah[kc], wrh[kc], rM);
            rC = MFMA(ah[kc], wrl[kc], rC);
            rC = MFMA(al[kc], wrh[kc], rC);
        }
        #pragma unroll
        for (int rg = 0; rg < 4; ++rg)
            RED(1, wv, qd * 4 + rg, nn) = rM[rg] + rC[rg] * LOINV;
        __syncthreads();

        float rsum = 0.f;
        #pragma unroll
        for (int w = 0; w < 4; ++w) rsum += RED(1, w, bq, iq);
        const float xr = xv.x * wr0 + xv.y * wr1;
        const float r  = 1.f / (1.f + expf(-(xr + rsum)));
        publish_val(exrh, bq * RR + i0 + iq, r * hprev, parA);
        __asm__ volatile("s_waitcnt vmcnt(0)" ::: "memory");

        // ===== phase B: u (fresh frags) + z (retained exh frags), h update =====
        f16x8 bh[4], bl[4];
        poll_frags(exrh, kb, lane, parA, bh, bl);

        f32x4 uM = {0,0,0,0}, uC = {0,0,0,0}, zM = {0,0,0,0}, zC = {0,0,0,0};
        #pragma unroll
        for (int kc = 0; kc < 4; ++kc) {
            uM = MFMA(bh[kc], whh[kc], uM);
            uC = MFMA(bh[kc], whl[kc], uC);
            uC = MFMA(bl[kc], whh[kc], uC);
            zM = MFMA(ah[kc], wzh[kc], zM);
            zC = MFMA(ah[kc], wzl[kc], zC);
            zC = MFMA(al[kc], wzh[kc], zC);
        }
        #pragma unroll
        for (int rg = 0; rg < 4; ++rg) {
            RED(2, wv, qd * 4 + rg, nn) = uM[rg] + uC[rg] * LOINV;
            RED(0, wv, qd * 4 + rg, nn) = zM[rg] + zC[rg] * LOINV;
        }
        __syncthreads();

        float usum = 0.f, zsum = 0.f;
        #pragma unroll
        for (int w = 0; w < 4; ++w) { usum += RED(2, w, bq, iq); zsum += RED(0, w, bq, iq); }
        const float u = xv.x * wh0 + xv.y * wh1 + usum;
        const float e2 = expf(-2.f * fabsf(u));
        const float th = copysignf((1.f - e2) / (1.f + e2), u);
        const float xz = xv.x * wz0 + xv.y * wz1;
        const float z  = 1.f / (1.f + expf(-(xz + zsum)));
        const float hn = hprev + DTAU * (z - 1.f) * (hprev - th);
        hprev = hn;
        publish_val(exh, bq * RR + i0 + iq, hn, parA ^ 1u);   // exh write #t+1
        __asm__ volatile("s_waitcnt vmcnt(0)" ::: "memory");
        h_out[((size_t)(b0 + bq) * T_ + t) * RR + i0 + iq] = hn;  // off the critical chain
    }
}

// ---------------- decoder: Y[m][n] = sum_k H[m][k] * Wd[n][k] (fp32) ----------------
#define DT_M 64
#define DT_N 64
#define DT_K 32

__global__ __launch_bounds__(256)
void decoder_gemm(const float* __restrict__ H, const float* __restrict__ Wd,
                  float* __restrict__ Y)
{
    __shared__ float As[DT_K][DT_M + 1];
    __shared__ float Bs[DT_K][DT_N + 1];
    const int m0 = blockIdx.x * DT_M;
    const int n0 = blockIdx.y * DT_N;
    const int tid = threadIdx.x;
    const int tx = tid % 16, ty = tid / 16;
    float acc[4][4] = {};

    for (int k0 = 0; k0 < RR; k0 += DT_K) {
        #pragma unroll
        for (int l = 0; l < 2; ++l) {
            int idx = tid + l * 256;
            int row = idx / (DT_K / 4);
            int kc  = idx % (DT_K / 4);
            float4 v = ((const float4*)&H[(size_t)(m0 + row) * RR + k0])[kc];
            As[kc * 4 + 0][row] = v.x; As[kc * 4 + 1][row] = v.y;
            As[kc * 4 + 2][row] = v.z; As[kc * 4 + 3][row] = v.w;
        }
        #pragma unroll
        for (int l = 0; l < 2; ++l) {
            int idx = tid + l * 256;
            int row = idx / (DT_K / 4);
            int kc  = idx % (DT_K / 4);
            float4 v = ((const float4*)&Wd[(size_t)(n0 + row) * RR + k0])[kc];
            Bs[kc * 4 + 0][row] = v.x; Bs[kc * 4 + 1][row] = v.y;
            Bs[kc * 4 + 2][row] = v.z; Bs[kc * 4 + 3][row] = v.w;
        }
        __syncthreads();
        #pragma unroll
        for (int k = 0; k < DT_K; ++k) {
            float a[4], bb[4];
            #pragma unroll
            for (int i2 = 0; i2 < 4; ++i2) a[i2] = As[k][ty * 4 + i2];
            #pragma unroll
            for (int j2 = 0; j2 < 4; ++j2) bb[j2] = Bs[k][tx * 4 + j2];
            #pragma unroll
            for (int i2 = 0; i2 < 4; ++i2)
                #pragma unroll
                for (int j2 = 0; j2 < 4; ++j2)
                    acc[i2][j2] += a[i2] * bb[j2];
        }
        __syncthreads();
    }
    #pragma unroll
    for (int i2 = 0; i2 < 4; ++i2) {
        float4 v = make_float4(acc[i2][0], acc[i2][1], acc[i2][2], acc[i2][3]);
        ((float4*)&Y[(size_t)(m0 + ty * 4 + i2) * RR + n0])[tx] = v;
    }
}

extern "C" void kernel_launch(void* const* d_in, const int* in_sizes, int n_in,
                              void* d_out, int out_size, void* d_ws, size_t ws_size,
                              hipStream_t stream) {
    const float* x          = (const float*)d_in[0];
    const float* init_state = (const float*)d_in[1];
    const float* W_enc      = (const float*)d_in[2];
    const float* W_wz       = (const float*)d_in[3];
    const float* W_uz       = (const float*)d_in[4];
    const float* W_wr       = (const float*)d_in[5];
    const float* W_ur       = (const float*)d_in[6];
    const float* W_wh       = (const float*)d_in[7];
    const float* W_uh       = (const float*)d_in[8];
    const float* W_dec      = (const float*)d_in[9];

    float* h_out = (float*)d_out;                          // [128][512][512]
    float* y_out = (float*)d_out + (size_t)B_ * T_ * RR;   // [128][512][512]
    unsigned int* ws = (unsigned int*)d_ws;

    init_parity<<<(EX_WORDS + 255) / 256, 256, 0, stream>>>(ws);
    rnn_persistent<<<NWG, NTHR, 0, stream>>>(
        x, init_state, W_enc, W_wz, W_uz, W_wr, W_ur, W_wh, W_uh, h_out, ws);
    decoder_gemm<<<dim3((B_ * T_) / DT_M, RR / DT_N), 256, 0, stream>>>(
        h_out, W_dec, y_out);
}

// Round 5
// 4062.317 us; speedup vs baseline: 1.3974x; 1.0387x over previous
//
#include <hip/hip_runtime.h>
#include <math.h>

#define B_   128
#define T_   512
#define RR   512
#define DTAU 0.2f

#define R_BLOCKS 32
#define B_BLOCKS 8
#define R_S  16
#define B_T  16
#define NWG  (R_BLOCKS * B_BLOCKS)
#define NTHR 256
#define LOSCALE 4096.0f
#define LOINV   (1.0f/4096.0f)

typedef _Float16 f16x8 __attribute__((ext_vector_type(8)));
typedef float f32x4 __attribute__((ext_vector_type(4)));

#define MFMA(A,B,C) __builtin_amdgcn_mfma_f32_16x16x32_f16(A, B, C, 0, 0, 0)

// ws layout in u32 units:
//   [0      .. 65536)  EX_H  : u32[128][512]
//   [65536  .. 131072) EX_RH : u32[128][512]
//   [131072 .. 393216) WD_PK : u32[512][512]  packed W_dec (hi|lo), if ws fits
// Each exchange u32 = hi f16 | lo' f16 << 16.  Bit 0 (hi-f16 LSB) carries the
// phase parity tag; lo is computed AFTER forcing the bit, so it compensates
// exactly.  No flags, no atomics.  Producers DO drain (s_waitcnt vmcnt(0))
// after each publish: measured (r1 vs r2/r3), the drain paces the producer
// until its store is ack'd at the coherence point — without it, consumer spin
// traffic doubles (FETCH 149->316 MB) and the phase period grows ~40%.
#define EXH_OFF  0
#define EXRH_OFF 65536
#define EX_WORDS 131072
#define WD_WORDS (RR * RR)

__global__ void init_parity(unsigned int* ws) {
    int i = blockIdx.x * 256 + threadIdx.x;
    if (i < EX_WORDS) ws[i] = 1u;   // parity=1 everywhere; first expected parity is 0
}

__device__ __forceinline__ unsigned long long ald64(const unsigned long long* p) {
    return __hip_atomic_load(p, __ATOMIC_RELAXED, __HIP_MEMORY_SCOPE_AGENT);
}

// Publish one value: force hi-f16 LSB := parity, recompute lo against the
// forced hi (exact compensation), store one u32 agent-scope.
__device__ __forceinline__ void publish_val(unsigned int* ex, int idx, float v,
                                            unsigned int par) {
    _Float16 vh = (_Float16)v;
    unsigned short hb =
        (unsigned short)((__builtin_bit_cast(unsigned short, vh) & 0xfffeu) | par);
    vh = __builtin_bit_cast(_Float16, hb);
    _Float16 vl = (_Float16)((v - (float)vh) * LOSCALE);
    unsigned int pk = (unsigned int)hb
                    | ((unsigned int)__builtin_bit_cast(unsigned short, vl) << 16);
    __hip_atomic_store(ex + idx, pk, __ATOMIC_RELAXED, __HIP_MEMORY_SCOPE_AGENT);
}

// Two-stage poll+load (measured-best r1 protocol).
// Stage 1: light pre-poll — 4 b64/lane covering 2 of 16 entries of EVERY
// producer slice in this wave's k-range; cheap body keeps detection fine-
// grained and MALL traffic low.
// Stage 2: single full fetch verifying EVERY u32's parity before use
// (re-loops only on a rare straggler race).
__device__ __forceinline__ void poll_frags(const unsigned int* ex, int kb, int lane,
                                           unsigned int want, f16x8* hi, f16x8* lo)
{
    const int b  = lane & 15;
    const int qd = lane >> 4;
    const unsigned long long wm = 0x0000000100000001ULL * (unsigned long long)want;
    const unsigned long long* p0 =
        (const unsigned long long*)(ex + (size_t)b * RR + kb + qd * 8);

    for (;;) {
        unsigned long long c0 = ald64(p0);
        unsigned long long c1 = ald64(p0 + 16);
        unsigned long long c2 = ald64(p0 + 32);
        unsigned long long c3 = ald64(p0 + 48);
        unsigned long long acc = (c0 ^ wm) | (c1 ^ wm) | (c2 ^ wm) | (c3 ^ wm);
        unsigned int a = (unsigned int)acc | (unsigned int)(acc >> 32);
        if (__all((a & 1u) == 0u)) break;
        __builtin_amdgcn_s_sleep(1);
    }
    __asm__ volatile("" ::: "memory");   // keep data loads after the spin exits

    for (;;) {
        unsigned long long d[16];
        #pragma unroll
        for (int kc = 0; kc < 4; ++kc)
            #pragma unroll
            for (int m = 0; m < 4; ++m)
                d[kc * 4 + m] = ald64(p0 + kc * 16 + m);
        unsigned long long acc = 0ull;
        #pragma unroll
        for (int i = 0; i < 16; ++i) acc |= d[i] ^ wm;
        unsigned int a = (unsigned int)acc | (unsigned int)(acc >> 32);
        if (__all((a & 1u) == 0u)) {
            #pragma unroll
            for (int kc = 0; kc < 4; ++kc) {
                union { f16x8 v; unsigned int u[4]; } H, L;
                #pragma unroll
                for (int m = 0; m < 4; ++m) {
                    unsigned int e0 = (unsigned int)d[kc * 4 + m];
                    unsigned int e1 = (unsigned int)(d[kc * 4 + m] >> 32);
                    H.u[m] = (e0 & 0xffffu) | (e1 << 16);
                    L.u[m] = (e0 >> 16) | (e1 & 0xffff0000u);
                }
                hi[kc] = H.v; lo[kc] = L.v;
            }
            __asm__ volatile("" ::: "memory");
            return;
        }
    }
}

// Pack 8 contiguous fp32 weights into hi + scaled-lo f16 fragments.
__device__ __forceinline__ void packW(const float* p, f16x8& hi, f16x8& lo) {
    float4 a = *(const float4*)p;
    float4 c = *(const float4*)(p + 4);
    float w[8] = {a.x, a.y, a.z, a.w, c.x, c.y, c.z, c.w};
    f16x8 H, L;
    #pragma unroll
    for (int j = 0; j < 8; ++j) {
        _Float16 h = (_Float16)w[j];
        H[j] = h;
        L[j] = (_Float16)((w[j] - (float)h) * LOSCALE);
    }
    hi = H; lo = L;
}

// Unpack 8 consecutive packed u32 (hi|lo<<16) into hi/lo fragments (bit-ops
// only; no float converts in the hot loop).
__device__ __forceinline__ void unpack8(const unsigned int* p, f16x8& hi, f16x8& lo) {
    const unsigned long long* q = (const unsigned long long*)p;
    union { f16x8 v; unsigned int u[4]; } H, L;
    #pragma unroll
    for (int m = 0; m < 4; ++m) {
        unsigned long long d = q[m];
        unsigned int e0 = (unsigned int)d;
        unsigned int e1 = (unsigned int)(d >> 32);
        H.u[m] = (e0 & 0xffffu) | (e1 << 16);
        L.u[m] = (e0 >> 16) | (e1 & 0xffff0000u);
    }
    hi = H.v; lo = L.v;
}

// LDS reduction planes: 1=r (phase A), 0=z and 2=u (phase B).  Disjoint
// planes + the per-phase barrier keep one __syncthreads per phase.
#define RED(g,w,m,n) sred[((((g)*4+(w))*16+(m))*17)+(n)]

__global__ __launch_bounds__(NTHR, 1)
void rnn_persistent(const float* __restrict__ x,
                    const float* __restrict__ init_state,
                    const float* __restrict__ W_enc,
                    const float* __restrict__ W_wz,
                    const float* __restrict__ W_uz,
                    const float* __restrict__ W_wr,
                    const float* __restrict__ W_ur,
                    const float* __restrict__ W_wh,
                    const float* __restrict__ W_uh,
                    float* __restrict__ h_out,   // [B][T][RR]
                    unsigned int* __restrict__ ws)
{
    const int wg = blockIdx.x;
    const int bg = wg & 7;           // batch group 0..7 (same XCD mod-8: perf only)
    const int rb = wg >> 3;          // r-slice 0..31
    const int b0 = bg * B_T;
    const int i0 = rb * R_S;

    unsigned int* exh  = ws + EXH_OFF  + (size_t)b0 * RR;
    unsigned int* exrh = ws + EXRH_OFF + (size_t)b0 * RR;

    __shared__ float sred[3 * 4 * 16 * 17];

    const int tid  = threadIdx.x;
    const int lane = tid & 63;
    const int wv   = tid >> 6;       // wave 0..3, owns K-slice [wv*128, wv*128+128)
    const int kb   = wv * 128;
    const int qd   = lane >> 4;
    const int nn   = lane & 15;
    const int bq   = tid >> 4;       // batch 0..15 (pointwise mapping)
    const int iq   = tid & 15;       // row-in-slice 0..15
    const int ig   = i0 + iq;

    const float wz0 = W_wz[ig * 2], wz1 = W_wz[ig * 2 + 1];
    const float wr0 = W_wr[ig * 2], wr1 = W_wr[ig * 2 + 1];
    const float wh0 = W_wh[ig * 2], wh1 = W_wh[ig * 2 + 1];

    // ---------------- encoder: h0 = init_state @ W_enc^T (fp32 exact) ----------------
    {
        float we[4][8];
        const int myrow = i0 + wv * 4;
        #pragma unroll
        for (int ii = 0; ii < 4; ++ii)
            #pragma unroll
            for (int j = 0; j < 8; ++j)
                we[ii][j] = W_enc[(size_t)(myrow + ii) * RR + lane + 64 * j];
        for (int b = 0; b < B_T; ++b) {
            float is[8];
            #pragma unroll
            for (int j = 0; j < 8; ++j)
                is[j] = init_state[(size_t)(b0 + b) * RR + lane + 64 * j];
            #pragma unroll
            for (int ii = 0; ii < 4; ++ii) {
                float acc = 0.f;
                #pragma unroll
                for (int j = 0; j < 8; ++j) acc += we[ii][j] * is[j];
                #pragma unroll
                for (int off = 32; off > 0; off >>= 1) acc += __shfl_xor(acc, off, 64);
                if (lane == 0) RED(0, 0, b, wv * 4 + ii) = acc;
            }
        }
    }
    __syncthreads();
    float hprev = RED(0, 0, bq, iq);
    publish_val(exh, bq * RR + i0 + iq, hprev, 0u);     // exh write #0, parity 0
    __asm__ volatile("s_waitcnt vmcnt(0)" ::: "memory");
    __syncthreads();   // hprev reads done before any wave writes RED plane 0

    // ---------------- pack recurrent weights to B-fragments in registers ----------------
    f16x8 wzh[4], wzl[4], wrh[4], wrl[4], whh[4], whl[4];
    #pragma unroll
    for (int kc = 0; kc < 4; ++kc) {
        const int kg = kb + kc * 32 + qd * 8;
        packW(&W_uz[(size_t)(i0 + nn) * RR + kg], wzh[kc], wzl[kc]);
        packW(&W_ur[(size_t)(i0 + nn) * RR + kg], wrh[kc], wrl[kc]);
        packW(&W_uh[(size_t)(i0 + nn) * RR + kg], whh[kc], whl[kc]);
    }

    // ---------------- time loop ----------------
    for (int t = 0; t < T_; ++t) {
        const unsigned int parA = (unsigned int)(t & 1);   // exh write #t / exrh write #t
        const float2 xv = ((const float2*)x)[(size_t)(b0 + bq) * T_ + t];

        // ===== phase A: r only (z's MFMAs are deferred to phase B) =====
        f16x8 ah[4], al[4];
        poll_frags(exh, kb, lane, parA, ah, al);

        f32x4 rM = {0,0,0,0}, rC = {0,0,0,0};
        #pragma unroll
        for (int kc = 0; kc < 4; ++kc) {
            rM = MFMA(ah[kc], wrh[kc], rM);
            rC = MFMA(ah[kc], wrl[kc], rC);
            rC = MFMA(al[kc], wrh[kc], rC);
        }
        #pragma unroll
        for (int rg = 0; rg < 4; ++rg)
            RED(1, wv, qd * 4 + rg, nn) = rM[rg] + rC[rg] * LOINV;
        __syncthreads();

        float rsum = 0.f;
        #pragma unroll
        for (int w = 0; w < 4; ++w) rsum += RED(1, w, bq, iq);
        const float xr = xv.x * wr0 + xv.y * wr1;
        const float r  = 1.f / (1.f + expf(-(xr + rsum)));
        publish_val(exrh, bq * RR + i0 + iq, r * hprev, parA);
        __asm__ volatile("s_waitcnt vmcnt(0)" ::: "memory");

        // ===== phase B: u (fresh frags) + z (retained exh frags), h update =====
        f16x8 bh[4], bl[4];
        poll_frags(exrh, kb, lane, parA, bh, bl);

        f32x4 uM = {0,0,0,0}, uC = {0,0,0,0}, zM = {0,0,0,0}, zC = {0,0,0,0};
        #pragma unroll
        for (int kc = 0; kc < 4; ++kc) {
            uM = MFMA(bh[kc], whh[kc], uM);
            uC = MFMA(bh[kc], whl[kc], uC);
            uC = MFMA(bl[kc], whh[kc], uC);
            zM = MFMA(ah[kc], wzh[kc], zM);
            zC = MFMA(ah[kc], wzl[kc], zC);
            zC = MFMA(al[kc], wzh[kc], zC);
        }
        #pragma unroll
        for (int rg = 0; rg < 4; ++rg) {
            RED(2, wv, qd * 4 + rg, nn) = uM[rg] + uC[rg] * LOINV;
            RED(0, wv, qd * 4 + rg, nn) = zM[rg] + zC[rg] * LOINV;
        }
        __syncthreads();

        float usum = 0.f, zsum = 0.f;
        #pragma unroll
        for (int w = 0; w < 4; ++w) { usum += RED(2, w, bq, iq); zsum += RED(0, w, bq, iq); }
        const float u = xv.x * wh0 + xv.y * wh1 + usum;
        const float e2 = expf(-2.f * fabsf(u));
        const float th = copysignf((1.f - e2) / (1.f + e2), u);
        const float xz = xv.x * wz0 + xv.y * wz1;
        const float z  = 1.f / (1.f + expf(-(xz + zsum)));
        const float hn = hprev + DTAU * (z - 1.f) * (hprev - th);
        hprev = hn;
        publish_val(exh, bq * RR + i0 + iq, hn, parA ^ 1u);   // exh write #t+1
        __asm__ volatile("s_waitcnt vmcnt(0)" ::: "memory");
        h_out[((size_t)(b0 + bq) * T_ + t) * RR + i0 + iq] = hn;  // off the critical chain
    }
}

// ---------------- decoder (MFMA path) ----------------
// Y[m][n] = sum_k H[m][k] * Wd[n][k], M=65536, N=512, K=512.
// Compensated hi/lo-f16: same numerics scheme as the rnn recurrent matmuls.
// W_dec is prepacked once into a 1 MB u32 plane (bit-unpack in the hot loop);
// H is converted on the fly (1 packW per wave per k-chunk).
__global__ void prepack_wd(const float* __restrict__ Wd, unsigned int* __restrict__ wp) {
    int i = blockIdx.x * 256 + threadIdx.x;   // 262144 total
    float v = Wd[i];
    _Float16 h = (_Float16)v;
    _Float16 l = (_Float16)((v - (float)h) * LOSCALE);
    wp[i] = (unsigned int)__builtin_bit_cast(unsigned short, h)
          | ((unsigned int)__builtin_bit_cast(unsigned short, l) << 16);
}

#define DM_M 32
#define DM_N 256

__global__ __launch_bounds__(256)
void decoder_mfma(const float* __restrict__ H, const unsigned int* __restrict__ Wdp,
                  float* __restrict__ Y)
{
    const int m0 = blockIdx.x * DM_M;
    const int n0 = blockIdx.y * DM_N;
    const int tid  = threadIdx.x;
    const int lane = tid & 63;
    const int wv   = tid >> 6;
    const int wy   = wv >> 1;          // m half (0..1)
    const int wx   = wv & 1;           // n half (0..1)
    const int nn   = lane & 15;
    const int qd   = lane >> 4;
    const int mrow = m0 + wy * 16 + nn;

    f32x4 accM[8], accC[8];
    #pragma unroll
    for (int nt = 0; nt < 8; ++nt) {
        accM[nt] = (f32x4){0,0,0,0};
        accC[nt] = (f32x4){0,0,0,0};
    }

    for (int k0 = 0; k0 < RR; k0 += 32) {
        const int kg = k0 + qd * 8;
        f16x8 ah, al;
        packW(&H[(size_t)mrow * RR + kg], ah, al);
        #pragma unroll
        for (int nt = 0; nt < 8; ++nt) {
            f16x8 bh, bl;
            unpack8(&Wdp[(size_t)(n0 + wx * 128 + nt * 16 + nn) * RR + kg], bh, bl);
            accM[nt] = MFMA(ah, bh, accM[nt]);
            accC[nt] = MFMA(ah, bl, accC[nt]);
            accC[nt] = MFMA(al, bh, accC[nt]);
        }
    }
    // C layout: row(m) = qd*4+rg, col(n) = nn
    #pragma unroll
    for (int nt = 0; nt < 8; ++nt)
        #pragma unroll
        for (int rg = 0; rg < 4; ++rg)
            Y[(size_t)(m0 + wy * 16 + qd * 4 + rg) * RR + n0 + wx * 128 + nt * 16 + nn]
                = accM[nt][rg] + accC[nt][rg] * LOINV;
}

// ---------------- decoder fallback (fp32 VALU, used if ws too small) ----------------
#define DT_M 64
#define DT_N 64
#define DT_K 32

__global__ __launch_bounds__(256)
void decoder_gemm(const float* __restrict__ H, const float* __restrict__ Wd,
                  float* __restrict__ Y)
{
    __shared__ float As[DT_K][DT_M + 1];
    __shared__ float Bs[DT_K][DT_N + 1];
    const int m0 = blockIdx.x * DT_M;
    const int n0 = blockIdx.y * DT_N;
    const int tid = threadIdx.x;
    const int tx = tid % 16, ty = tid / 16;
    float acc[4][4] = {};

    for (int k0 = 0; k0 < RR; k0 += DT_K) {
        #pragma unroll
        for (int l = 0; l < 2; ++l) {
            int idx = tid + l * 256;
            int row = idx / (DT_K / 4);
            int kc  = idx % (DT_K / 4);
            float4 v = ((const float4*)&H[(size_t)(m0 + row) * RR + k0])[kc];
            As[kc * 4 + 0][row] = v.x; As[kc * 4 + 1][row] = v.y;
            As[kc * 4 + 2][row] = v.z; As[kc * 4 + 3][row] = v.w;
        }
        #pragma unroll
        for (int l = 0; l < 2; ++l) {
            int idx = tid + l * 256;
            int row = idx / (DT_K / 4);
            int kc  = idx % (DT_K / 4);
            float4 v = ((const float4*)&Wd[(size_t)(n0 + row) * RR + k0])[kc];
            Bs[kc * 4 + 0][row] = v.x; Bs[kc * 4 + 1][row] = v.y;
            Bs[kc * 4 + 2][row] = v.z; Bs[kc * 4 + 3][row] = v.w;
        }
        __syncthreads();
        #pragma unroll
        for (int k = 0; k < DT_K; ++k) {
            float a[4], bb[4];
            #pragma unroll
            for (int i2 = 0; i2 < 4; ++i2) a[i2] = As[k][ty * 4 + i2];
            #pragma unroll
            for (int j2 = 0; j2 < 4; ++j2) bb[j2] = Bs[k][tx * 4 + j2];
            #pragma unroll
            for (int i2 = 0; i2 < 4; ++i2)
                #pragma unroll
                for (int j2 = 0; j2 < 4; ++j2)
                    acc[i2][j2] += a[i2] * bb[j2];
        }
        __syncthreads();
    }
    #pragma unroll
    for (int i2 = 0; i2 < 4; ++i2) {
        float4 v = make_float4(acc[i2][0], acc[i2][1], acc[i2][2], acc[i2][3]);
        ((float4*)&Y[(size_t)(m0 + ty * 4 + i2) * RR + n0])[tx] = v;
    }
}

extern "C" void kernel_launch(void* const* d_in, const int* in_sizes, int n_in,
                              void* d_out, int out_size, void* d_ws, size_t ws_size,
                              hipStream_t stream) {
    const float* x          = (const float*)d_in[0];
    const float* init_state = (const float*)d_in[1];
    const float* W_enc      = (const float*)d_in[2];
    const float* W_wz       = (const float*)d_in[3];
    const float* W_uz       = (const float*)d_in[4];
    const float* W_wr       = (const float*)d_in[5];
    const float* W_ur       = (const float*)d_in[6];
    const float* W_wh       = (const float*)d_in[7];
    const float* W_uh       = (const float*)d_in[8];
    const float* W_dec      = (const float*)d_in[9];

    float* h_out = (float*)d_out;                          // [128][512][512]
    float* y_out = (float*)d_out + (size_t)B_ * T_ * RR;   // [128][512][512]
    unsigned int* ws = (unsigned int*)d_ws;

    const bool big_ws = ws_size >= (size_t)(EX_WORDS + WD_WORDS) * 4;

    init_parity<<<(EX_WORDS + 255) / 256, 256, 0, stream>>>(ws);
    if (big_ws)
        prepack_wd<<<WD_WORDS / 256, 256, 0, stream>>>(W_dec, ws + EX_WORDS);
    rnn_persistent<<<NWG, NTHR, 0, stream>>>(
        x, init_state, W_enc, W_wz, W_uz, W_wr, W_ur, W_wh, W_uh, h_out, ws);
    if (big_ws)
        decoder_mfma<<<dim3((B_ * T_) / DM_M, RR / DM_N), 256, 0, stream>>>(
            h_out, ws + EX_WORDS, y_out);
    else
        decoder_gemm<<<dim3((B_ * T_) / DT_M, RR / DT_N), 256, 0, stream>>>(
            h_out, W_dec, y_out);
}

// Round 6
// 3803.637 us; speedup vs baseline: 1.4924x; 1.0680x over previous
//
#include <hip/hip_runtime.h>
#include <math.h>

#define B_   128
#define T_   512
#define RR   512
#define DTAU 0.2f

#define R_BLOCKS 32
#define B_BLOCKS 8
#define R_S  16
#define B_T  16
#define NWG  (R_BLOCKS * B_BLOCKS)
#define NTHR 256
#define LOSCALE 4096.0f
#define LOINV   (1.0f/4096.0f)

typedef _Float16 f16x8 __attribute__((ext_vector_type(8)));
typedef float f32x4 __attribute__((ext_vector_type(4)));

#define MFMA(A,B,C) __builtin_amdgcn_mfma_f32_16x16x32_f16(A, B, C, 0, 0, 0)

// ws layout in u32 units:
//   [0      .. 65536)  EX_H  : u32[128][512]
//   [65536  .. 131072) EX_RH : u32[128][512]
//   [131072 .. 393216) WD_PK : packed W_dec in FRAGMENT ORDER (see prepack_wd)
// Each exchange u32 = hi f16 | lo' f16 << 16.  Bit 0 (hi-f16 LSB) carries the
// phase parity tag; lo is computed AFTER forcing the bit, so it compensates
// exactly.  No flags, no atomics.  Producers DO drain (s_waitcnt vmcnt(0))
// after each publish: measured (r1 vs r2/r3), the drain paces the producer
// until its store is ack'd at the coherence point — without it, consumer spin
// traffic doubles (FETCH 149->316 MB) and the phase period grows ~40%.
#define EXH_OFF  0
#define EXRH_OFF 65536
#define EX_WORDS 131072
#define WD_WORDS (RR * RR)

__global__ void init_parity(unsigned int* ws) {
    int i = blockIdx.x * 256 + threadIdx.x;
    if (i < EX_WORDS) ws[i] = 1u;   // parity=1 everywhere; first expected parity is 0
}

__device__ __forceinline__ unsigned long long ald64(const unsigned long long* p) {
    return __hip_atomic_load(p, __ATOMIC_RELAXED, __HIP_MEMORY_SCOPE_AGENT);
}

// Publish one value: force hi-f16 LSB := parity, recompute lo against the
// forced hi (exact compensation), store one u32 agent-scope.
__device__ __forceinline__ void publish_val(unsigned int* ex, int idx, float v,
                                            unsigned int par) {
    _Float16 vh = (_Float16)v;
    unsigned short hb =
        (unsigned short)((__builtin_bit_cast(unsigned short, vh) & 0xfffeu) | par);
    vh = __builtin_bit_cast(_Float16, hb);
    _Float16 vl = (_Float16)((v - (float)vh) * LOSCALE);
    unsigned int pk = (unsigned int)hb
                    | ((unsigned int)__builtin_bit_cast(unsigned short, vl) << 16);
    __hip_atomic_store(ex + idx, pk, __ATOMIC_RELAXED, __HIP_MEMORY_SCOPE_AGENT);
}

// Two-stage poll+load (measured-best r1 protocol).
// Stage 1: light pre-poll — 4 b64/lane covering 2 of 16 entries of EVERY
// producer slice in this wave's k-range; cheap body keeps detection fine-
// grained and MALL traffic low.
// Stage 2: single full fetch verifying EVERY u32's parity before use
// (re-loops only on a rare straggler race).
__device__ __forceinline__ void poll_frags(const unsigned int* ex, int kb, int lane,
                                           unsigned int want, f16x8* hi, f16x8* lo)
{
    const int b  = lane & 15;
    const int qd = lane >> 4;
    const unsigned long long wm = 0x0000000100000001ULL * (unsigned long long)want;
    const unsigned long long* p0 =
        (const unsigned long long*)(ex + (size_t)b * RR + kb + qd * 8);

    for (;;) {
        unsigned long long c0 = ald64(p0);
        unsigned long long c1 = ald64(p0 + 16);
        unsigned long long c2 = ald64(p0 + 32);
        unsigned long long c3 = ald64(p0 + 48);
        unsigned long long acc = (c0 ^ wm) | (c1 ^ wm) | (c2 ^ wm) | (c3 ^ wm);
        unsigned int a = (unsigned int)acc | (unsigned int)(acc >> 32);
        if (__all((a & 1u) == 0u)) break;
        __builtin_amdgcn_s_sleep(1);
    }
    __asm__ volatile("" ::: "memory");   // keep data loads after the spin exits

    for (;;) {
        unsigned long long d[16];
        #pragma unroll
        for (int kc = 0; kc < 4; ++kc)
            #pragma unroll
            for (int m = 0; m < 4; ++m)
                d[kc * 4 + m] = ald64(p0 + kc * 16 + m);
        unsigned long long acc = 0ull;
        #pragma unroll
        for (int i = 0; i < 16; ++i) acc |= d[i] ^ wm;
        unsigned int a = (unsigned int)acc | (unsigned int)(acc >> 32);
        if (__all((a & 1u) == 0u)) {
            #pragma unroll
            for (int kc = 0; kc < 4; ++kc) {
                union { f16x8 v; unsigned int u[4]; } H, L;
                #pragma unroll
                for (int m = 0; m < 4; ++m) {
                    unsigned int e0 = (unsigned int)d[kc * 4 + m];
                    unsigned int e1 = (unsigned int)(d[kc * 4 + m] >> 32);
                    H.u[m] = (e0 & 0xffffu) | (e1 << 16);
                    L.u[m] = (e0 >> 16) | (e1 & 0xffff0000u);
                }
                hi[kc] = H.v; lo[kc] = L.v;
            }
            __asm__ volatile("" ::: "memory");
            return;
        }
    }
}

// Pack 8 contiguous fp32 weights into hi + scaled-lo f16 fragments.
__device__ __forceinline__ void packW(const float* p, f16x8& hi, f16x8& lo) {
    float4 a = *(const float4*)p;
    float4 c = *(const float4*)(p + 4);
    float w[8] = {a.x, a.y, a.z, a.w, c.x, c.y, c.z, c.w};
    f16x8 H, L;
    #pragma unroll
    for (int j = 0; j < 8; ++j) {
        _Float16 h = (_Float16)w[j];
        H[j] = h;
        L[j] = (_Float16)((w[j] - (float)h) * LOSCALE);
    }
    hi = H; lo = L;
}

// Unpack 8 consecutive packed u32 (hi|lo<<16) into hi/lo fragments (bit-ops
// only; no float converts in the hot loop).
__device__ __forceinline__ void unpack8(const unsigned int* p, f16x8& hi, f16x8& lo) {
    const unsigned long long* q = (const unsigned long long*)p;
    union { f16x8 v; unsigned int u[4]; } H, L;
    #pragma unroll
    for (int m = 0; m < 4; ++m) {
        unsigned long long d = q[m];
        unsigned int e0 = (unsigned int)d;
        unsigned int e1 = (unsigned int)(d >> 32);
        H.u[m] = (e0 & 0xffffu) | (e1 << 16);
        L.u[m] = (e0 >> 16) | (e1 & 0xffff0000u);
    }
    hi = H.v; lo = L.v;
}

// LDS reduction planes: 1=r (phase A), 0=z and 2=u (phase B).  Disjoint
// planes + the per-phase barrier keep one __syncthreads per phase.
#define RED(g,w,m,n) sred[((((g)*4+(w))*16+(m))*17)+(n)]

__global__ __launch_bounds__(NTHR, 1)
void rnn_persistent(const float* __restrict__ x,
                    const float* __restrict__ init_state,
                    const float* __restrict__ W_enc,
                    const float* __restrict__ W_wz,
                    const float* __restrict__ W_uz,
                    const float* __restrict__ W_wr,
                    const float* __restrict__ W_ur,
                    const float* __restrict__ W_wh,
                    const float* __restrict__ W_uh,
                    float* __restrict__ h_out,   // [B][T][RR]
                    unsigned int* __restrict__ ws)
{
    const int wg = blockIdx.x;
    const int bg = wg & 7;           // batch group 0..7 (same XCD mod-8: perf only)
    const int rb = wg >> 3;          // r-slice 0..31
    const int b0 = bg * B_T;
    const int i0 = rb * R_S;

    unsigned int* exh  = ws + EXH_OFF  + (size_t)b0 * RR;
    unsigned int* exrh = ws + EXRH_OFF + (size_t)b0 * RR;

    __shared__ float sred[3 * 4 * 16 * 17];

    const int tid  = threadIdx.x;
    const int lane = tid & 63;
    const int wv   = tid >> 6;       // wave 0..3, owns K-slice [wv*128, wv*128+128)
    const int kb   = wv * 128;
    const int qd   = lane >> 4;
    const int nn   = lane & 15;
    const int bq   = tid >> 4;       // batch 0..15 (pointwise mapping)
    const int iq   = tid & 15;       // row-in-slice 0..15
    const int ig   = i0 + iq;

    const float wz0 = W_wz[ig * 2], wz1 = W_wz[ig * 2 + 1];
    const float wr0 = W_wr[ig * 2], wr1 = W_wr[ig * 2 + 1];
    const float wh0 = W_wh[ig * 2], wh1 = W_wh[ig * 2 + 1];

    // ---------------- encoder: h0 = init_state @ W_enc^T (fp32 exact) ----------------
    {
        float we[4][8];
        const int myrow = i0 + wv * 4;
        #pragma unroll
        for (int ii = 0; ii < 4; ++ii)
            #pragma unroll
            for (int j = 0; j < 8; ++j)
                we[ii][j] = W_enc[(size_t)(myrow + ii) * RR + lane + 64 * j];
        for (int b = 0; b < B_T; ++b) {
            float is[8];
            #pragma unroll
            for (int j = 0; j < 8; ++j)
                is[j] = init_state[(size_t)(b0 + b) * RR + lane + 64 * j];
            #pragma unroll
            for (int ii = 0; ii < 4; ++ii) {
                float acc = 0.f;
                #pragma unroll
                for (int j = 0; j < 8; ++j) acc += we[ii][j] * is[j];
                #pragma unroll
                for (int off = 32; off > 0; off >>= 1) acc += __shfl_xor(acc, off, 64);
                if (lane == 0) RED(0, 0, b, wv * 4 + ii) = acc;
            }
        }
    }
    __syncthreads();
    float hprev = RED(0, 0, bq, iq);
    publish_val(exh, bq * RR + i0 + iq, hprev, 0u);     // exh write #0, parity 0
    __asm__ volatile("s_waitcnt vmcnt(0)" ::: "memory");
    __syncthreads();   // hprev reads done before any wave writes RED plane 0

    // ---------------- pack recurrent weights to B-fragments in registers ----------------
    f16x8 wzh[4], wzl[4], wrh[4], wrl[4], whh[4], whl[4];
    #pragma unroll
    for (int kc = 0; kc < 4; ++kc) {
        const int kg = kb + kc * 32 + qd * 8;
        packW(&W_uz[(size_t)(i0 + nn) * RR + kg], wzh[kc], wzl[kc]);
        packW(&W_ur[(size_t)(i0 + nn) * RR + kg], wrh[kc], wrl[kc]);
        packW(&W_uh[(size_t)(i0 + nn) * RR + kg], whh[kc], whl[kc]);
    }

    // ---------------- time loop ----------------
    for (int t = 0; t < T_; ++t) {
        const unsigned int parA = (unsigned int)(t & 1);   // exh write #t / exrh write #t
        const float2 xv = ((const float2*)x)[(size_t)(b0 + bq) * T_ + t];

        // ===== phase A: r only (z's MFMAs are deferred to phase B) =====
        f16x8 ah[4], al[4];
        poll_frags(exh, kb, lane, parA, ah, al);

        f32x4 rM = {0,0,0,0}, rC = {0,0,0,0};
        #pragma unroll
        for (int kc = 0; kc < 4; ++kc) {
            rM = MFMA(ah[kc], wrh[kc], rM);
            rC = MFMA(ah[kc], wrl[kc], rC);
            rC = MFMA(al[kc], wrh[kc], rC);
        }
        #pragma unroll
        for (int rg = 0; rg < 4; ++rg)
            RED(1, wv, qd * 4 + rg, nn) = rM[rg] + rC[rg] * LOINV;
        __syncthreads();

        float rsum = 0.f;
        #pragma unroll
        for (int w = 0; w < 4; ++w) rsum += RED(1, w, bq, iq);
        const float xr = xv.x * wr0 + xv.y * wr1;
        const float r  = 1.f / (1.f + expf(-(xr + rsum)));
        publish_val(exrh, bq * RR + i0 + iq, r * hprev, parA);
        __asm__ volatile("s_waitcnt vmcnt(0)" ::: "memory");

        // ===== phase B: u (fresh frags) + z (retained exh frags), h update =====
        f16x8 bh[4], bl[4];
        poll_frags(exrh, kb, lane, parA, bh, bl);

        f32x4 uM = {0,0,0,0}, uC = {0,0,0,0}, zM = {0,0,0,0}, zC = {0,0,0,0};
        #pragma unroll
        for (int kc = 0; kc < 4; ++kc) {
            uM = MFMA(bh[kc], whh[kc], uM);
            uC = MFMA(bh[kc], whl[kc], uC);
            uC = MFMA(bl[kc], whh[kc], uC);
            zM = MFMA(ah[kc], wzh[kc], zM);
            zC = MFMA(ah[kc], wzl[kc], zC);
            zC = MFMA(al[kc], wzh[kc], zC);
        }
        #pragma unroll
        for (int rg = 0; rg < 4; ++rg) {
            RED(2, wv, qd * 4 + rg, nn) = uM[rg] + uC[rg] * LOINV;
            RED(0, wv, qd * 4 + rg, nn) = zM[rg] + zC[rg] * LOINV;
        }
        __syncthreads();

        float usum = 0.f, zsum = 0.f;
        #pragma unroll
        for (int w = 0; w < 4; ++w) { usum += RED(2, w, bq, iq); zsum += RED(0, w, bq, iq); }
        const float u = xv.x * wh0 + xv.y * wh1 + usum;
        const float e2 = expf(-2.f * fabsf(u));
        const float th = copysignf((1.f - e2) / (1.f + e2), u);
        const float xz = xv.x * wz0 + xv.y * wz1;
        const float z  = 1.f / (1.f + expf(-(xz + zsum)));
        const float hn = hprev + DTAU * (z - 1.f) * (hprev - th);
        hprev = hn;
        publish_val(exh, bq * RR + i0 + iq, hn, parA ^ 1u);   // exh write #t+1
        __asm__ volatile("s_waitcnt vmcnt(0)" ::: "memory");
        h_out[((size_t)(b0 + bq) * T_ + t) * RR + i0 + iq] = hn;  // off the critical chain
    }
}

// ---------------- decoder (MFMA path) ----------------
// Y[m][n] = sum_k H[m][k] * Wd[n][k], M=65536, N=512, K=512.
// Compensated hi/lo-f16: same numerics scheme as the rnn recurrent matmuls.
// W_dec is prepacked once into FRAGMENT ORDER: one 512-u32 block per
// (n-tile of 16, k-chunk of 32); within a block, lane l's 8 B-frag words sit
// at [l*8 .. l*8+8).  The decoder B-load is then a fully coalesced,
// layout-math-free 2 KB/wave contiguous read (the r5 version's per-lane
// 2KB-strided gathers cost ~16 cache-line transactions per instruction and
// left the decoder ~10x off the MFMA floor).
__global__ void prepack_wd(const float* __restrict__ Wd, unsigned int* __restrict__ wp) {
    const int o      = blockIdx.x * 256 + threadIdx.x;   // 262144 total
    const int blk    = o >> 9;        // 512 u32 per fragment block
    const int within = o & 511;
    const int ln     = within >> 3;   // lane 0..63
    const int j      = within & 7;
    const int ntg    = blk >> 4;      // n-tile 0..31
    const int kc     = blk & 15;      // k-chunk 0..15
    const int n = ntg * 16 + (ln & 15);
    const int k = kc * 32 + (ln >> 4) * 8 + j;
    const float v = Wd[(size_t)n * RR + k];
    _Float16 h = (_Float16)v;
    _Float16 l = (_Float16)((v - (float)h) * LOSCALE);
    wp[o] = (unsigned int)__builtin_bit_cast(unsigned short, h)
          | ((unsigned int)__builtin_bit_cast(unsigned short, l) << 16);
}

#define DM_M 32
#define DM_N 256

__global__ __launch_bounds__(256)
void decoder_mfma(const float* __restrict__ H, const unsigned int* __restrict__ Wdp,
                  float* __restrict__ Y)
{
    const int m0 = blockIdx.x * DM_M;
    const int n0 = blockIdx.y * DM_N;
    const int tid  = threadIdx.x;
    const int lane = tid & 63;
    const int wv   = tid >> 6;
    const int wy   = wv >> 1;          // m half (0..1)
    const int wx   = wv & 1;           // n half (0..1)
    const int nn   = lane & 15;
    const int qd   = lane >> 4;
    const int mrow = m0 + wy * 16 + nn;
    const int ng0  = (n0 + wx * 128) >> 4;   // first n-tile index for this wave

    f32x4 accM[8], accC[8];
    #pragma unroll
    for (int nt = 0; nt < 8; ++nt) {
        accM[nt] = (f32x4){0,0,0,0};
        accC[nt] = (f32x4){0,0,0,0};
    }

    for (int kc = 0; kc < 16; ++kc) {
        const int kg = kc * 32 + qd * 8;
        f16x8 ah, al;
        packW(&H[(size_t)mrow * RR + kg], ah, al);
        #pragma unroll
        for (int nt = 0; nt < 8; ++nt) {
            f16x8 bh, bl;
            unpack8(Wdp + (((size_t)(ng0 + nt) * 16 + kc) << 9) + lane * 8, bh, bl);
            accM[nt] = MFMA(ah, bh, accM[nt]);
            accC[nt] = MFMA(ah, bl, accC[nt]);
            accC[nt] = MFMA(al, bh, accC[nt]);
        }
    }
    // C layout: row(m) = qd*4+rg, col(n) = nn
    #pragma unroll
    for (int nt = 0; nt < 8; ++nt)
        #pragma unroll
        for (int rg = 0; rg < 4; ++rg)
            Y[(size_t)(m0 + wy * 16 + qd * 4 + rg) * RR + n0 + wx * 128 + nt * 16 + nn]
                = accM[nt][rg] + accC[nt][rg] * LOINV;
}

// ---------------- decoder fallback (fp32 VALU, used if ws too small) ----------------
#define DT_M 64
#define DT_N 64
#define DT_K 32

__global__ __launch_bounds__(256)
void decoder_gemm(const float* __restrict__ H, const float* __restrict__ Wd,
                  float* __restrict__ Y)
{
    __shared__ float As[DT_K][DT_M + 1];
    __shared__ float Bs[DT_K][DT_N + 1];
    const int m0 = blockIdx.x * DT_M;
    const int n0 = blockIdx.y * DT_N;
    const int tid = threadIdx.x;
    const int tx = tid % 16, ty = tid / 16;
    float acc[4][4] = {};

    for (int k0 = 0; k0 < RR; k0 += DT_K) {
        #pragma unroll
        for (int l = 0; l < 2; ++l) {
            int idx = tid + l * 256;
            int row = idx / (DT_K / 4);
            int kc  = idx % (DT_K / 4);
            float4 v = ((const float4*)&H[(size_t)(m0 + row) * RR + k0])[kc];
            As[kc * 4 + 0][row] = v.x; As[kc * 4 + 1][row] = v.y;
            As[kc * 4 + 2][row] = v.z; As[kc * 4 + 3][row] = v.w;
        }
        #pragma unroll
        for (int l = 0; l < 2; ++l) {
            int idx = tid + l * 256;
            int row = idx / (DT_K / 4);
            int kc  = idx % (DT_K / 4);
            float4 v = ((const float4*)&Wd[(size_t)(n0 + row) * RR + k0])[kc];
            Bs[kc * 4 + 0][row] = v.x; Bs[kc * 4 + 1][row] = v.y;
            Bs[kc * 4 + 2][row] = v.z; Bs[kc * 4 + 3][row] = v.w;
        }
        __syncthreads();
        #pragma unroll
        for (int k = 0; k < DT_K; ++k) {
            float a[4], bb[4];
            #pragma unroll
            for (int i2 = 0; i2 < 4; ++i2) a[i2] = As[k][ty * 4 + i2];
            #pragma unroll
            for (int j2 = 0; j2 < 4; ++j2) bb[j2] = Bs[k][tx * 4 + j2];
            #pragma unroll
            for (int i2 = 0; i2 < 4; ++i2)
                #pragma unroll
                for (int j2 = 0; j2 < 4; ++j2)
                    acc[i2][j2] += a[i2] * bb[j2];
        }
        __syncthreads();
    }
    #pragma unroll
    for (int i2 = 0; i2 < 4; ++i2) {
        float4 v = make_float4(acc[i2][0], acc[i2][1], acc[i2][2], acc[i2][3]);
        ((float4*)&Y[(size_t)(m0 + ty * 4 + i2) * RR + n0])[tx] = v;
    }
}

extern "C" void kernel_launch(void* const* d_in, const int* in_sizes, int n_in,
                              void* d_out, int out_size, void* d_ws, size_t ws_size,
                              hipStream_t stream) {
    const float* x          = (const float*)d_in[0];
    const float* init_state = (const float*)d_in[1];
    const float* W_enc      = (const float*)d_in[2];
    const float* W_wz       = (const float*)d_in[3];
    const float* W_uz       = (const float*)d_in[4];
    const float* W_wr       = (const float*)d_in[5];
    const float* W_ur       = (const float*)d_in[6];
    const float* W_wh       = (const float*)d_in[7];
    const float* W_uh       = (const float*)d_in[8];
    const float* W_dec      = (const float*)d_in[9];

    float* h_out = (float*)d_out;                          // [128][512][512]
    float* y_out = (float*)d_out + (size_t)B_ * T_ * RR;   // [128][512][512]
    unsigned int* ws = (unsigned int*)d_ws;

    const bool big_ws = ws_size >= (size_t)(EX_WORDS + WD_WORDS) * 4;

    init_parity<<<(EX_WORDS + 255) / 256, 256, 0, stream>>>(ws);
    if (big_ws)
        prepack_wd<<<WD_WORDS / 256, 256, 0, stream>>>(W_dec, ws + EX_WORDS);
    rnn_persistent<<<NWG, NTHR, 0, stream>>>(
        x, init_state, W_enc, W_wz, W_uz, W_wr, W_ur, W_wh, W_uh, h_out, ws);
    if (big_ws)
        decoder_mfma<<<dim3((B_ * T_) / DM_M, RR / DM_N), 256, 0, stream>>>(
            h_out, ws + EX_WORDS, y_out);
    else
        decoder_gemm<<<dim3((B_ * T_) / DT_M, RR / DT_N), 256, 0, stream>>>(
            h_out, W_dec, y_out);
}